// Round 3
// baseline (79.980 us; speedup 1.0000x reference)
//
#include <hip/hip_runtime.h>

#define NUM_ATOMS 3
#define MAX_NODES 15
#define VPT 8           // columns (j) per thread
#define ROWS 2          // rows (i) per block
#define EPS_K 1e-6f
#define LOG2E 1.4426950408889634f

__device__ __forceinline__ float fexp2(float a) {
#if __has_builtin(__builtin_amdgcn_exp2f)
    return __builtin_amdgcn_exp2f(a);     // v_exp_f32: D = 2^S0
#else
    return exp2f(a);
#endif
}
// sin(2*pi*a) — hardware v_sin_f32 takes REVOLUTIONS; |a| here <= ~4 revs.
__device__ __forceinline__ float fsin_rev(float a) {
#if __has_builtin(__builtin_amdgcn_sinf)
    return __builtin_amdgcn_sinf(a);
#else
    return __sinf(a * 6.283185307179586f);
#endif
}

// Leaf body expanded directly into the destination stack registers (DST is a
// float[ROWS][VPT] identifier -> all indexing static, no scratch, no tmp movs).
#define DO_LEAF(DST)                                                          \
    do {                                                                      \
        if (v == 0) {                       /* rbf: p0^2 * 2^(dx^2*c1) */     \
            const float c1 = -0.5f * LOG2E / (p1 * p1 + EPS_K);               \
            _Pragma("unroll")                                                 \
            for (int r = 0; r < ROWS; ++r) {                                  \
                _Pragma("unroll")                                             \
                for (int k = 0; k < VPT; ++k) {                               \
                    const float dx = xi[r] - yv[k];                           \
                    DST[r][k] = p0sq * fexp2(dx * dx * c1);                   \
                }                                                             \
            }                                                                 \
        } else if (v == 1) {                /* linear */                      \
            const float p1sq = p1 * p1;                                       \
            _Pragma("unroll")                                                 \
            for (int r = 0; r < ROWS; ++r) {                                  \
                const float a_ = p0sq * xi[r];                                \
                _Pragma("unroll")                                             \
                for (int k = 0; k < VPT; ++k)                                 \
                    DST[r][k] = fmaf(a_, yv[k], p1sq);                        \
            }                                                                 \
        } else {                            /* periodic */                    \
            const float inv2p = 0.5f / (p2 * p2 + 1.0f);                      \
            const float c2    = -2.0f * LOG2E / (p1 * p1 + EPS_K);            \
            _Pragma("unroll")                                                 \
            for (int r = 0; r < ROWS; ++r) {                                  \
                _Pragma("unroll")                                             \
                for (int k = 0; k < VPT; ++k) {                               \
                    const float s = fsin_rev((xi[r] - yv[k]) * inv2p);        \
                    DST[r][k] = p0sq * fexp2(s * s * c2);                     \
                }                                                             \
            }                                                                 \
        }                                                                     \
    } while (0)

// Operator: D = op(S, D)  (l=stack[ptr-1]=S, r=stack[ptr-2]=D; add/mul commutative)
#define DO_OP(D, S)                                                           \
    do {                                                                      \
        _Pragma("unroll")                                                     \
        for (int r = 0; r < ROWS; ++r) {                                      \
            _Pragma("unroll")                                                 \
            for (int k = 0; k < VPT; ++k)                                     \
                D[r][k] = isAdd ? (S[r][k] + D[r][k]) : (S[r][k] * D[r][k]);  \
        }                                                                     \
    } while (0)

__global__ __launch_bounds__(256) void tree_eval_kernel(
    const float* __restrict__ x, const float* __restrict__ y,
    const int* __restrict__ expr, const int* __restrict__ lvl,
    const float* __restrict__ params, float* __restrict__ out, int d2)
{
    __shared__ int   s_expr[MAX_NODES];
    __shared__ int   s_lvl[MAX_NODES];
    __shared__ float s_par[MAX_NODES][3];
    if (threadIdx.x < MAX_NODES) {
        const int t = threadIdx.x;
        s_expr[t]   = expr[t];
        s_lvl[t]    = lvl[t];
        s_par[t][0] = params[3 * t + 0];
        s_par[t][1] = params[3 * t + 1];
        s_par[t][2] = params[3 * t + 2];
    }
    __syncthreads();

    const int i0 = blockIdx.x * ROWS;
    const int jb = threadIdx.x * VPT;

    float xi[ROWS];
#pragma unroll
    for (int r = 0; r < ROWS; ++r) xi[r] = x[i0 + r];

    float yv[VPT];
    {
        const float4* y4 = reinterpret_cast<const float4*>(y + jb);
        float4 a = y4[0], b = y4[1];
        yv[0] = a.x; yv[1] = a.y; yv[2] = a.z; yv[3] = a.w;
        yv[4] = b.x; yv[5] = b.y; yv[6] = b.z; yv[7] = b.w;
    }

    // 4-deep stack in registers; ptr is uniform -> no divergence.
    float s0[ROWS][VPT], s1[ROWS][VPT], s2[ROWS][VPT], s3[ROWS][VPT];
#pragma unroll
    for (int r = 0; r < ROWS; ++r)
#pragma unroll
        for (int k = 0; k < VPT; ++k) {
            s0[r][k] = 0.f; s1[r][k] = 0.f; s2[r][k] = 0.f; s3[r][k] = 0.f;
        }

    int ptr = 0;
    for (int n = 0; n < MAX_NODES; ++n) {
        const int v = s_expr[n];
        if (v < 0) continue;

        if (v >= NUM_ATOMS) {
            const bool isAdd = (v == NUM_ATOMS);   // 3->add, >=4->mul
            switch (ptr) {
                case 2:  DO_OP(s0, s1); break;
                case 3:  DO_OP(s1, s2); break;
                default: DO_OP(s2, s3); break;
            }
            ptr -= 1;
        } else {
            const int   L  = s_lvl[n];
            const float p0 = s_par[L][0], p1 = s_par[L][1], p2 = s_par[L][2];
            const float p0sq = p0 * p0;
            switch (ptr) {
                case 0:  DO_LEAF(s0); break;
                case 1:  DO_LEAF(s1); break;
                case 2:  DO_LEAF(s2); break;
                default: DO_LEAF(s3); break;
            }
            ptr += 1;
        }
    }

    // result = stack[0]; write ROWS x VPT block, coalesced float4s.
#pragma unroll
    for (int r = 0; r < ROWS; ++r) {
        float4 o0 = make_float4(s0[r][0], s0[r][1], s0[r][2], s0[r][3]);
        float4 o1 = make_float4(s0[r][4], s0[r][5], s0[r][6], s0[r][7]);
        float4* o4 = reinterpret_cast<float4*>(out + (size_t)(i0 + r) * d2 + jb);
        o4[0] = o0;
        o4[1] = o1;
    }
}

extern "C" void kernel_launch(void* const* d_in, const int* in_sizes, int n_in,
                              void* d_out, int out_size, void* d_ws, size_t ws_size,
                              hipStream_t stream) {
    const float* x      = (const float*)d_in[0];
    const float* y      = (const float*)d_in[1];
    const int*   expr   = (const int*)d_in[2];
    const int*   lvl    = (const int*)d_in[3];
    const float* params = (const float*)d_in[5];
    float*       out    = (float*)d_out;

    const int d1 = in_sizes[0];
    const int d2 = in_sizes[1];

    dim3 grid(d1 / ROWS);      // 1024
    dim3 block(d2 / VPT);      // 256
    tree_eval_kernel<<<grid, block, 0, stream>>>(x, y, expr, lvl, params, out, d2);
}

// Round 4
// 78.957 us; speedup vs baseline: 1.0130x; 1.0130x over previous
//
#include <hip/hip_runtime.h>

#define NUM_ATOMS 3
#define MAX_NODES 15
#define VPT 8           // elements (j values) per thread
#define EPS_K 1e-6f
#define LOG2E 1.4426950408889634f

__device__ __forceinline__ float fexp2(float a) {
#if __has_builtin(__builtin_amdgcn_exp2f)
    return __builtin_amdgcn_exp2f(a);     // v_exp_f32: D = 2^S0
#else
    return exp2f(a);
#endif
}
// sin(2*pi*a) — hardware v_sin_f32 takes REVOLUTIONS; |a| here <= ~4 revs.
__device__ __forceinline__ float fsin_rev(float a) {
#if __has_builtin(__builtin_amdgcn_sinf)
    return __builtin_amdgcn_sinf(a);
#else
    return __sinf(a * 6.283185307179586f);
#endif
}

// Leaf body expanded directly into destination stack registers (DST is a
// float[VPT] identifier -> static indexing, no scratch, no tmp movs).
#define DO_LEAF(DST)                                                          \
    do {                                                                      \
        if (v == 0) {                       /* rbf: p0^2 * 2^(dx^2*c1) */     \
            const float c1 = -0.5f * LOG2E / (p1 * p1 + EPS_K);               \
            _Pragma("unroll")                                                 \
            for (int k = 0; k < VPT; ++k) {                                   \
                const float dx = xi - yv[k];                                  \
                DST[k] = p0sq * fexp2(dx * dx * c1);                          \
            }                                                                 \
        } else if (v == 1) {                /* linear */                      \
            const float a_   = p0sq * xi;                                     \
            const float p1sq = p1 * p1;                                       \
            _Pragma("unroll")                                                 \
            for (int k = 0; k < VPT; ++k)                                     \
                DST[k] = fmaf(a_, yv[k], p1sq);                               \
        } else {                            /* periodic */                    \
            const float inv2p = 0.5f / (p2 * p2 + 1.0f);                      \
            const float c2    = -2.0f * LOG2E / (p1 * p1 + EPS_K);            \
            _Pragma("unroll")                                                 \
            for (int k = 0; k < VPT; ++k) {                                   \
                const float s = fsin_rev((xi - yv[k]) * inv2p);               \
                DST[k] = p0sq * fexp2(s * s * c2);                            \
            }                                                                 \
        }                                                                     \
    } while (0)

// Operator: D = op(S, D)  (l=stack[ptr-1]=S, r=stack[ptr-2]=D; add/mul commutative)
#define DO_OP(D, S)                                                           \
    do {                                                                      \
        _Pragma("unroll")                                                     \
        for (int k = 0; k < VPT; ++k)                                         \
            D[k] = isAdd ? (S[k] + D[k]) : (S[k] * D[k]);                     \
    } while (0)

__global__ __launch_bounds__(256) void tree_eval_kernel(
    const float* __restrict__ x, const float* __restrict__ y,
    const int* __restrict__ expr, const int* __restrict__ lvl,
    const float* __restrict__ params, float* __restrict__ out, int d2)
{
    __shared__ int   s_expr[MAX_NODES];
    __shared__ int   s_lvl[MAX_NODES];
    __shared__ float s_par[MAX_NODES][3];
    if (threadIdx.x < MAX_NODES) {
        const int t = threadIdx.x;
        s_expr[t]   = expr[t];
        s_lvl[t]    = lvl[t];
        s_par[t][0] = params[3 * t + 0];
        s_par[t][1] = params[3 * t + 1];
        s_par[t][2] = params[3 * t + 2];
    }
    __syncthreads();

    const int   i  = blockIdx.x;
    const int   jb = threadIdx.x * VPT;
    const float xi = x[i];

    float yv[VPT];
    {
        const float4* y4 = reinterpret_cast<const float4*>(y + jb);
        float4 a = y4[0], b = y4[1];
        yv[0] = a.x; yv[1] = a.y; yv[2] = a.z; yv[3] = a.w;
        yv[4] = b.x; yv[5] = b.y; yv[6] = b.z; yv[7] = b.w;
    }

    // 4-deep stack in registers; ptr is uniform -> no divergence.
    // No zero-init: any valid post-order expression writes a stack slot
    // (leaf) before it is ever read (operator), and out = s0 requires at
    // least one push.
    float s0[VPT], s1[VPT], s2[VPT], s3[VPT];

    int ptr = 0;
    for (int n = 0; n < MAX_NODES; ++n) {
        const int v = s_expr[n];
        if (v < 0) continue;

        if (v >= NUM_ATOMS) {
            const bool isAdd = (v == NUM_ATOMS);   // 3->add, >=4->mul
            switch (ptr) {
                case 2:  DO_OP(s0, s1); break;
                case 3:  DO_OP(s1, s2); break;
                default: DO_OP(s2, s3); break;
            }
            ptr -= 1;
        } else {
            const int   L  = s_lvl[n];
            const float p0 = s_par[L][0], p1 = s_par[L][1], p2 = s_par[L][2];
            const float p0sq = p0 * p0;
            switch (ptr) {
                case 0:  DO_LEAF(s0); break;
                case 1:  DO_LEAF(s1); break;
                case 2:  DO_LEAF(s2); break;
                default: DO_LEAF(s3); break;
            }
            ptr += 1;
        }
    }

    float4 o0 = make_float4(s0[0], s0[1], s0[2], s0[3]);
    float4 o1 = make_float4(s0[4], s0[5], s0[6], s0[7]);
    float4* o4 = reinterpret_cast<float4*>(out + (size_t)i * d2 + jb);
    o4[0] = o0;
    o4[1] = o1;
}

extern "C" void kernel_launch(void* const* d_in, const int* in_sizes, int n_in,
                              void* d_out, int out_size, void* d_ws, size_t ws_size,
                              hipStream_t stream) {
    const float* x      = (const float*)d_in[0];
    const float* y      = (const float*)d_in[1];
    const int*   expr   = (const int*)d_in[2];
    const int*   lvl    = (const int*)d_in[3];
    const float* params = (const float*)d_in[5];
    float*       out    = (float*)d_out;

    const int d1 = in_sizes[0];
    const int d2 = in_sizes[1];

    dim3 grid(d1);            // 2048
    dim3 block(d2 / VPT);     // 256
    tree_eval_kernel<<<grid, block, 0, stream>>>(x, y, expr, lvl, params, out, d2);
}